// Round 2
// baseline (1892.943 us; speedup 1.0000x reference)
//
#include <hip/hip_runtime.h>
#include <math.h>

#define SEQ 4096
#define DM  1024
#define NH  16
#define DH  64

// ---------------------------------------------------------------------------
// GEMM: C[M][N] = A[M][K] @ B[N][K]^T   (all row-major fp32)
// 64x64 tile, BK=16, 256 threads, 4x4 micro-tile per thread.
// LDS k-major (As[kk][m]) so the inner loop does float4 LDS reads.
// ---------------------------------------------------------------------------
__global__ __launch_bounds__(256) void gemm_abt(const float* __restrict__ A,
                                                const float* __restrict__ B,
                                                float* __restrict__ C,
                                                int M, int N, int K) {
    __shared__ float As[16][68];   // [kk][m], pad 68 -> 272B row stride (16B aligned)
    __shared__ float Bs[16][68];   // [kk][n]

    const int t  = threadIdx.x;
    const int tx = t & 15;         // 0..15 -> n
    const int ty = t >> 4;         // 0..15 -> m
    const int m0 = blockIdx.y * 64;
    const int n0 = blockIdx.x * 64;

    const int lr = t >> 2;         // 0..63 load row
    const int lc = (t & 3) * 4;    // 0,4,8,12 load col (float4)

    float acc[4][4] = {};

    for (int k0 = 0; k0 < K; k0 += 16) {
        const float4 av = *(const float4*)(A + (size_t)(m0 + lr) * K + k0 + lc);
        As[lc + 0][lr] = av.x; As[lc + 1][lr] = av.y;
        As[lc + 2][lr] = av.z; As[lc + 3][lr] = av.w;
        const float4 bv = *(const float4*)(B + (size_t)(n0 + lr) * K + k0 + lc);
        Bs[lc + 0][lr] = bv.x; Bs[lc + 1][lr] = bv.y;
        Bs[lc + 2][lr] = bv.z; Bs[lc + 3][lr] = bv.w;
        __syncthreads();

        #pragma unroll
        for (int kk = 0; kk < 16; ++kk) {
            const float4 a = *(const float4*)&As[kk][ty * 4];
            const float4 b = *(const float4*)&Bs[kk][tx * 4];
            const float ar[4] = {a.x, a.y, a.z, a.w};
            const float br[4] = {b.x, b.y, b.z, b.w};
            #pragma unroll
            for (int i = 0; i < 4; ++i)
                #pragma unroll
                for (int j = 0; j < 4; ++j)
                    acc[i][j] = fmaf(ar[i], br[j], acc[i][j]);
        }
        __syncthreads();
    }

    #pragma unroll
    for (int i = 0; i < 4; ++i) {
        float4 v = make_float4(acc[i][0], acc[i][1], acc[i][2], acc[i][3]);
        *(float4*)(C + (size_t)(m0 + ty * 4 + i) * N + n0 + tx * 4) = v;
    }
}

// ---------------------------------------------------------------------------
// Flash attention (causal), fp32. One block = (head, 64-query tile).
// Q,K,V,O layout: (S, D) row-major, head h occupies cols [h*64, h*64+64).
// Online softmax; accumulator 4x4 per thread (64x64 O tile).
// ---------------------------------------------------------------------------
__global__ __launch_bounds__(256) void flash_attn(const float* __restrict__ Q,
                                                  const float* __restrict__ K,
                                                  const float* __restrict__ V,
                                                  float* __restrict__ O) {
    __shared__ float Qs[64][68];   // d-major: Qs[d][qi]
    __shared__ float Ks[64][68];   // d-major: Ks[d][kj]
    __shared__ float Vs[64][68];   // row-major: Vs[kk][dj]
    __shared__ float Ps[64][68];   // scores/probs: Ps[qi][kj]
    __shared__ float m_s[64], l_s[64], alpha_s[64];

    const int qt = 63 - (int)blockIdx.x;   // heavy tiles dispatched first
    const int h  = blockIdx.y;
    const int t  = threadIdx.x;
    const int tx = t & 15;
    const int ty = t >> 4;
    const int q0 = qt * 64;
    const int hc = h * DH;

    const int lr = t >> 2;         // 0..63 row within tile
    const int lc = (t & 3) * 4;    // 0,4,8,12 base col; cols lc+16c, c=0..3 cover 0..63

    // load Q tile (transposed into d-major) — 64x64: 4 float4s per thread
    #pragma unroll
    for (int c = 0; c < 4; ++c) {
        const int d0 = lc + 16 * c;
        const float4 qv = *(const float4*)(Q + (size_t)(q0 + lr) * DM + hc + d0);
        Qs[d0 + 0][lr] = qv.x; Qs[d0 + 1][lr] = qv.y;
        Qs[d0 + 2][lr] = qv.z; Qs[d0 + 3][lr] = qv.w;
    }
    if (t < 64) { m_s[t] = -1e30f; l_s[t] = 0.0f; }

    float acc[4][4] = {};
    const float scale = 0.125f;   // 1/sqrt(64)

    __syncthreads();

    for (int kt = 0; kt <= qt; ++kt) {
        const int k0 = kt * 64;
        // stage K (d-major) and V (row-major) — full 64x64 tiles
        #pragma unroll
        for (int c = 0; c < 4; ++c) {
            const int d0 = lc + 16 * c;
            const float4 kv = *(const float4*)(K + (size_t)(k0 + lr) * DM + hc + d0);
            Ks[d0 + 0][lr] = kv.x; Ks[d0 + 1][lr] = kv.y;
            Ks[d0 + 2][lr] = kv.z; Ks[d0 + 3][lr] = kv.w;
            const float4 vv = *(const float4*)(V + (size_t)(k0 + lr) * DM + hc + d0);
            *(float4*)&Vs[lr][d0] = vv;
        }
        __syncthreads();

        // S = Q K^T (4x4 per thread)
        float s[4][4] = {};
        #pragma unroll 8
        for (int d = 0; d < 64; ++d) {
            const float4 a = *(const float4*)&Qs[d][ty * 4];
            const float4 b = *(const float4*)&Ks[d][tx * 4];
            const float ar[4] = {a.x, a.y, a.z, a.w};
            const float br[4] = {b.x, b.y, b.z, b.w};
            #pragma unroll
            for (int i = 0; i < 4; ++i)
                #pragma unroll
                for (int j = 0; j < 4; ++j)
                    s[i][j] = fmaf(ar[i], br[j], s[i][j]);
        }

        const bool diag = (kt == qt);
        #pragma unroll
        for (int i = 0; i < 4; ++i) {
            float4 v;
            float* sv = &v.x;
            #pragma unroll
            for (int j = 0; j < 4; ++j) {
                float val = s[i][j] * scale;
                if (diag && (tx * 4 + j) > (ty * 4 + i)) val = -1e30f;
                sv[j] = val;
            }
            *(float4*)&Ps[ty * 4 + i][tx * 4] = v;
        }
        __syncthreads();

        // online softmax update (one thread per query row)
        if (t < 64) {
            const float mold = m_s[t];
            float mx = mold;
            #pragma unroll 8
            for (int j = 0; j < 64; ++j) mx = fmaxf(mx, Ps[t][j]);
            const float alpha = __expf(mold - mx);
            float sum = 0.0f;
            #pragma unroll 8
            for (int j = 0; j < 64; ++j) {
                const float p = __expf(Ps[t][j] - mx);
                Ps[t][j] = p;
                sum += p;
            }
            m_s[t] = mx;
            l_s[t] = l_s[t] * alpha + sum;
            alpha_s[t] = alpha;
        }
        __syncthreads();

        // rescale accumulator, then O += P @ V
        float al[4];
        #pragma unroll
        for (int i = 0; i < 4; ++i) al[i] = alpha_s[ty * 4 + i];
        #pragma unroll
        for (int i = 0; i < 4; ++i)
            #pragma unroll
            for (int j = 0; j < 4; ++j)
                acc[i][j] *= al[i];

        #pragma unroll 8
        for (int kk = 0; kk < 64; ++kk) {
            const float4 vv = *(const float4*)&Vs[kk][tx * 4];
            const float vr[4] = {vv.x, vv.y, vv.z, vv.w};
            const float pr[4] = {Ps[ty * 4 + 0][kk], Ps[ty * 4 + 1][kk],
                                 Ps[ty * 4 + 2][kk], Ps[ty * 4 + 3][kk]};
            #pragma unroll
            for (int i = 0; i < 4; ++i)
                #pragma unroll
                for (int j = 0; j < 4; ++j)
                    acc[i][j] = fmaf(pr[i], vr[j], acc[i][j]);
        }
        __syncthreads();   // protect Ks/Vs/Ps before next tile
    }

    // epilogue: O = acc / l
    float linv[4];
    #pragma unroll
    for (int i = 0; i < 4; ++i) linv[i] = 1.0f / l_s[ty * 4 + i];
    #pragma unroll
    for (int i = 0; i < 4; ++i) {
        float4 v = make_float4(acc[i][0] * linv[i], acc[i][1] * linv[i],
                               acc[i][2] * linv[i], acc[i][3] * linv[i]);
        *(float4*)(O + (size_t)(q0 + ty * 4 + i) * DM + hc + tx * 4) = v;
    }
}

extern "C" void kernel_launch(void* const* d_in, const int* in_sizes, int n_in,
                              void* d_out, int out_size, void* d_ws, size_t ws_size,
                              hipStream_t stream) {
    const float* x  = (const float*)d_in[0];
    const float* Wq = (const float*)d_in[1];
    const float* Wk = (const float*)d_in[2];
    const float* Wv = (const float*)d_in[3];
    const float* Wo = (const float*)d_in[4];
    float* out = (float*)d_out;

    float* Q  = (float*)d_ws;
    float* K  = Q + (size_t)SEQ * DM;
    float* V  = K + (size_t)SEQ * DM;
    float* AO = V + (size_t)SEQ * DM;

    dim3 blk(256);
    dim3 ggrid(DM / 64, SEQ / 64);   // (N/64, M/64)

    gemm_abt<<<ggrid, blk, 0, stream>>>(x, Wq, Q, SEQ, DM, DM);
    gemm_abt<<<ggrid, blk, 0, stream>>>(x, Wk, K, SEQ, DM, DM);
    gemm_abt<<<ggrid, blk, 0, stream>>>(x, Wv, V, SEQ, DM, DM);

    flash_attn<<<dim3(SEQ / 64, NH), blk, 0, stream>>>(Q, K, V, AO);

    gemm_abt<<<ggrid, blk, 0, stream>>>(AO, Wo, out, SEQ, DM, DM);
}

// Round 3
// 386.153 us; speedup vs baseline: 4.9021x; 4.9021x over previous
//
#include <hip/hip_runtime.h>
#include <math.h>

#define SEQ 4096
#define DM  1024
#define NH  16
#define DH  64

typedef _Float16 h16;
typedef __attribute__((ext_vector_type(4))) _Float16 h16x4;
typedef __attribute__((ext_vector_type(8))) _Float16 h16x8;
typedef __attribute__((ext_vector_type(4))) float f32x4;

// ---------------------------------------------------------------------------
// fp32 -> fp16 conversion, vectorized (n must be multiple of 4)
// ---------------------------------------------------------------------------
__global__ __launch_bounds__(256) void cvt_f32_f16(const float* __restrict__ in,
                                                   h16* __restrict__ out, int n4) {
    const int i = blockIdx.x * 256 + threadIdx.x;
    if (i < n4) {
        const float4 v = ((const float4*)in)[i];
        h16x4 o = { (h16)v.x, (h16)v.y, (h16)v.z, (h16)v.w };
        ((h16x4*)out)[i] = o;
    }
}

// ---------------------------------------------------------------------------
// MFMA GEMM: C[M][N] = A[M][K] @ B[N][K]^T, fp16 in, fp32 accumulate.
// 128x128 tile, BK=32, 256 threads = 4 waves (2x2 of 64x64), reg-prefetch.
// OUT: 0 = h16 row-major [M][N]; 1 = h16 transposed [N][M]; 2 = f32 [M][N].
// LDS row stride 40 h16 (80 B): frag-read lanes hit every bank exactly 2-way.
// ---------------------------------------------------------------------------
#define GST 40

template<int OUT>
__global__ __launch_bounds__(256) void gemm_mfma(const h16* __restrict__ A,
                                                 const h16* __restrict__ B,
                                                 void* __restrict__ Cv,
                                                 int M, int N, int K) {
    __shared__ h16 As[128 * GST];
    __shared__ h16 Bs[128 * GST];

    const int t    = threadIdx.x;
    const int lane = t & 63;
    const int w    = t >> 6;
    const int wm   = (w >> 1) * 64;
    const int wn   = (w & 1) * 64;
    const int l15  = lane & 15;
    const int lq8  = (lane >> 4) * 8;
    const int m0   = blockIdx.y * 128;
    const int n0   = blockIdx.x * 128;

    const int lrow = t >> 2;          // 0..63 (covers rows r and r+64)
    const int lcol = (t & 3) * 8;     // 0,8,16,24 within BK=32

    f32x4 acc[4][4] = {};

    const h16* pA0 = A + (size_t)(m0 + lrow) * K + lcol;
    const h16* pA1 = A + (size_t)(m0 + 64 + lrow) * K + lcol;
    const h16* pB0 = B + (size_t)(n0 + lrow) * K + lcol;
    const h16* pB1 = B + (size_t)(n0 + 64 + lrow) * K + lcol;

    h16x8 ra0 = *(const h16x8*)pA0;
    h16x8 ra1 = *(const h16x8*)pA1;
    h16x8 rb0 = *(const h16x8*)pB0;
    h16x8 rb1 = *(const h16x8*)pB1;

    for (int k0 = 0; k0 < K; k0 += 32) {
        __syncthreads();
        *(h16x8*)&As[lrow * GST + lcol]        = ra0;
        *(h16x8*)&As[(64 + lrow) * GST + lcol] = ra1;
        *(h16x8*)&Bs[lrow * GST + lcol]        = rb0;
        *(h16x8*)&Bs[(64 + lrow) * GST + lcol] = rb1;
        __syncthreads();
        if (k0 + 32 < K) {   // prefetch next slab (latency hidden by MFMAs)
            ra0 = *(const h16x8*)(pA0 + k0 + 32);
            ra1 = *(const h16x8*)(pA1 + k0 + 32);
            rb0 = *(const h16x8*)(pB0 + k0 + 32);
            rb1 = *(const h16x8*)(pB1 + k0 + 32);
        }
        h16x8 af[4], bf[4];
        #pragma unroll
        for (int i = 0; i < 4; ++i)
            af[i] = *(const h16x8*)&As[(wm + i * 16 + l15) * GST + lq8];
        #pragma unroll
        for (int j = 0; j < 4; ++j)
            bf[j] = *(const h16x8*)&Bs[(wn + j * 16 + l15) * GST + lq8];
        #pragma unroll
        for (int i = 0; i < 4; ++i)
            #pragma unroll
            for (int j = 0; j < 4; ++j)
                acc[i][j] = __builtin_amdgcn_mfma_f32_16x16x32_f16(af[i], bf[j], acc[i][j], 0, 0, 0);
    }

    // C/D layout: col = lane&15, row = (lane>>4)*4 + r  [m89/m91 verified]
    const int cr = wm + (lane >> 4) * 4;
    const int cc = wn + l15;
    #pragma unroll
    for (int i = 0; i < 4; ++i)
        #pragma unroll
        for (int j = 0; j < 4; ++j)
            #pragma unroll
            for (int r = 0; r < 4; ++r) {
                const int gm = m0 + cr + i * 16 + r;
                const int gn = n0 + cc + j * 16;
                if (OUT == 2)      ((float*)Cv)[(size_t)gm * N + gn] = acc[i][j][r];
                else if (OUT == 0) ((h16*)Cv)[(size_t)gm * N + gn] = (h16)acc[i][j][r];
                else               ((h16*)Cv)[(size_t)gn * M + gm] = (h16)acc[i][j][r];
            }
}

// ---------------------------------------------------------------------------
// MFMA flash attention (causal). Block = (q-tile of 64, head). 4 waves;
// wave w owns q rows [16w, 16w+16). V is consumed pre-transposed (Vt[d][s]).
// Softmax state in registers (per quad-row), reduced via shfl_xor(1,2,4,8).
// P: C-layout -> A-layout via per-wave LDS round-trip (in-wave waitcnt only).
// ---------------------------------------------------------------------------
#define AST 72   // 64 + 8 pad: frag reads 2-way max, 16B aligned rows

__global__ __launch_bounds__(256, 4) void flash_attn_mfma(
        const h16* __restrict__ Qg, const h16* __restrict__ Kg,
        const h16* __restrict__ Vt, h16* __restrict__ Og) {
    __shared__ h16 Qs[64 * AST];
    __shared__ h16 Ks[64 * AST];
    __shared__ h16 Vs[64 * AST];   // [d][k]
    __shared__ h16 Ps[64 * AST];   // [q][k], per-wave 16-row bands

    const int qt   = 63 - (int)blockIdx.x;   // heavy tiles first
    const int hh   = blockIdx.y;
    const int t    = threadIdx.x;
    const int lane = t & 63;
    const int w    = t >> 6;
    const int l15  = lane & 15;
    const int lq   = lane >> 4;
    const int lq8  = lq * 8;
    const int q0   = qt * 64;
    const int hc   = hh * DH;
    const int row_l = w * 16 + lq * 4;

    // staging map: 64x64 tile = 512 16B chunks; thread t does chunks t, t+256
    const int r1 = t >> 3;            // rows 0..31
    const int r2 = r1 + 32;           // rows 32..63
    const int c1 = (t & 7) * 8;

    // Q tile -> LDS (once)
    {
        const h16x8 q1 = *(const h16x8*)(Qg + (size_t)(q0 + r1) * DM + hc + c1);
        const h16x8 q2 = *(const h16x8*)(Qg + (size_t)(q0 + r2) * DM + hc + c1);
        *(h16x8*)&Qs[r1 * AST + c1] = q1;
        *(h16x8*)&Qs[r2 * AST + c1] = q2;
    }
    // preload first K/V tiles into regs
    h16x8 kv1 = *(const h16x8*)(Kg + (size_t)(r1) * DM + hc + c1);
    h16x8 kv2 = *(const h16x8*)(Kg + (size_t)(r2) * DM + hc + c1);
    h16x8 vv1 = *(const h16x8*)(Vt + (size_t)(hc + r1) * SEQ + c1);
    h16x8 vv2 = *(const h16x8*)(Vt + (size_t)(hc + r2) * SEQ + c1);

    __syncthreads();
    const h16x8 qf0 = *(const h16x8*)&Qs[(w * 16 + l15) * AST + lq8];
    const h16x8 qf1 = *(const h16x8*)&Qs[(w * 16 + l15) * AST + 32 + lq8];

    float m_st[4] = {-1e30f, -1e30f, -1e30f, -1e30f};
    float l_st[4] = {};
    f32x4 o_acc[4] = {};
    const float scale = 0.125f;   // 1/sqrt(64)

    for (int kt = 0; kt <= qt; ++kt) {
        __syncthreads();   // prior iter's Ks/Vs reads done
        *(h16x8*)&Ks[r1 * AST + c1] = kv1;
        *(h16x8*)&Ks[r2 * AST + c1] = kv2;
        *(h16x8*)&Vs[r1 * AST + c1] = vv1;
        *(h16x8*)&Vs[r2 * AST + c1] = vv2;
        __syncthreads();
        if (kt < qt) {   // prefetch next K/V tiles
            const int k0n = (kt + 1) * 64;
            kv1 = *(const h16x8*)(Kg + (size_t)(k0n + r1) * DM + hc + c1);
            kv2 = *(const h16x8*)(Kg + (size_t)(k0n + r2) * DM + hc + c1);
            vv1 = *(const h16x8*)(Vt + (size_t)(hc + r1) * SEQ + k0n + c1);
            vv2 = *(const h16x8*)(Vt + (size_t)(hc + r2) * SEQ + k0n + c1);
        }

        // ---- S = Q K^T (16 q-rows x 64 k-cols per wave) ----
        f32x4 sj[4] = {};
        #pragma unroll
        for (int j = 0; j < 4; ++j) {
            const h16x8 kf = *(const h16x8*)&Ks[(j * 16 + l15) * AST + lq8];
            sj[j] = __builtin_amdgcn_mfma_f32_16x16x32_f16(qf0, kf, sj[j], 0, 0, 0);
        }
        #pragma unroll
        for (int j = 0; j < 4; ++j) {
            const h16x8 kf = *(const h16x8*)&Ks[(j * 16 + l15) * AST + 32 + lq8];
            sj[j] = __builtin_amdgcn_mfma_f32_16x16x32_f16(qf1, kf, sj[j], 0, 0, 0);
        }

        // ---- scale + causal mask ----
        const bool diag = (kt == qt);
        float sv[4][4];
        #pragma unroll
        for (int j = 0; j < 4; ++j)
            #pragma unroll
            for (int r = 0; r < 4; ++r) {
                float x = sj[j][r] * scale;
                if (diag && (j * 16 + l15) > (row_l + r)) x = -1e30f;
                sv[j][r] = x;
            }

        // ---- online softmax (row state per quad-row, shfl over 16 lanes) ----
        float rmax[4], alpha[4], rsum[4];
        #pragma unroll
        for (int r = 0; r < 4; ++r)
            rmax[r] = fmaxf(fmaxf(sv[0][r], sv[1][r]), fmaxf(sv[2][r], sv[3][r]));
        #pragma unroll
        for (int msk = 1; msk <= 8; msk <<= 1)
            #pragma unroll
            for (int r = 0; r < 4; ++r)
                rmax[r] = fmaxf(rmax[r], __shfl_xor(rmax[r], msk, 64));
        #pragma unroll
        for (int r = 0; r < 4; ++r) {
            const float mn = fmaxf(m_st[r], rmax[r]);
            alpha[r] = __expf(m_st[r] - mn);
            m_st[r]  = mn;
            rsum[r]  = 0.0f;
        }
        #pragma unroll
        for (int j = 0; j < 4; ++j)
            #pragma unroll
            for (int r = 0; r < 4; ++r) {
                const float p = __expf(sv[j][r] - m_st[r]);
                rsum[r] += p;
                Ps[(row_l + r) * AST + j * 16 + l15] = (h16)p;
            }
        #pragma unroll
        for (int msk = 1; msk <= 8; msk <<= 1)
            #pragma unroll
            for (int r = 0; r < 4; ++r)
                rsum[r] += __shfl_xor(rsum[r], msk, 64);
        #pragma unroll
        for (int r = 0; r < 4; ++r)
            l_st[r] = l_st[r] * alpha[r] + rsum[r];

        // rescale O while P stores drain
        #pragma unroll
        for (int j = 0; j < 4; ++j)
            #pragma unroll
            for (int r = 0; r < 4; ++r)
                o_acc[j][r] *= alpha[r];

        // ---- O += P V  (P via per-wave LDS round-trip; in-wave ordering) ----
        asm volatile("s_waitcnt lgkmcnt(0)" ::: "memory");
        const h16x8 pf0 = *(const h16x8*)&Ps[(w * 16 + l15) * AST + lq8];
        const h16x8 pf1 = *(const h16x8*)&Ps[(w * 16 + l15) * AST + 32 + lq8];
        #pragma unroll
        for (int j = 0; j < 4; ++j) {
            const h16x8 vf0 = *(const h16x8*)&Vs[(j * 16 + l15) * AST + lq8];
            o_acc[j] = __builtin_amdgcn_mfma_f32_16x16x32_f16(pf0, vf0, o_acc[j], 0, 0, 0);
            const h16x8 vf1 = *(const h16x8*)&Vs[(j * 16 + l15) * AST + 32 + lq8];
            o_acc[j] = __builtin_amdgcn_mfma_f32_16x16x32_f16(pf1, vf1, o_acc[j], 0, 0, 0);
        }
    }

    // ---- epilogue: O /= l ----
    #pragma unroll
    for (int r = 0; r < 4; ++r) {
        const float inv = 1.0f / l_st[r];
        #pragma unroll
        for (int j = 0; j < 4; ++j)
            Og[(size_t)(q0 + row_l + r) * DM + hc + j * 16 + l15] = (h16)(o_acc[j][r] * inv);
    }
}

// ---------------------------------------------------------------------------
extern "C" void kernel_launch(void* const* d_in, const int* in_sizes, int n_in,
                              void* d_out, int out_size, void* d_ws, size_t ws_size,
                              hipStream_t stream) {
    const float* x  = (const float*)d_in[0];
    const float* Wq = (const float*)d_in[1];
    const float* Wk = (const float*)d_in[2];
    const float* Wv = (const float*)d_in[3];
    const float* Wo = (const float*)d_in[4];
    float* out = (float*)d_out;

    const size_t SD = (size_t)SEQ * DM;   // 4M
    const size_t DD = (size_t)DM * DM;    // 1M

    h16* xh  = (h16*)d_ws;
    h16* wqh = xh + SD;
    h16* wkh = wqh + DD;
    h16* wvh = wkh + DD;
    h16* woh = wvh + DD;
    h16* Qh  = woh + DD;
    h16* Kh  = Qh + SD;
    h16* Vth = Kh + SD;     // transposed: [DM][SEQ]
    h16* AOh = Vth + SD;

    // convert inputs to fp16
    cvt_f32_f16<<<(int)(SD / 4 / 256), 256, 0, stream>>>(x,  xh,  (int)(SD / 4));
    cvt_f32_f16<<<(int)(DD / 4 / 256), 256, 0, stream>>>(Wq, wqh, (int)(DD / 4));
    cvt_f32_f16<<<(int)(DD / 4 / 256), 256, 0, stream>>>(Wk, wkh, (int)(DD / 4));
    cvt_f32_f16<<<(int)(DD / 4 / 256), 256, 0, stream>>>(Wv, wvh, (int)(DD / 4));
    cvt_f32_f16<<<(int)(DD / 4 / 256), 256, 0, stream>>>(Wo, woh, (int)(DD / 4));

    const dim3 blk(256);
    const dim3 gg(DM / 128, SEQ / 128);   // (8, 32)

    gemm_mfma<0><<<gg, blk, 0, stream>>>(xh, wqh, Qh,  SEQ, DM, DM);
    gemm_mfma<0><<<gg, blk, 0, stream>>>(xh, wkh, Kh,  SEQ, DM, DM);
    gemm_mfma<1><<<gg, blk, 0, stream>>>(xh, wvh, Vth, SEQ, DM, DM);   // V^T out

    flash_attn_mfma<<<dim3(SEQ / 64, NH), blk, 0, stream>>>(Qh, Kh, Vth, AOh);

    gemm_mfma<2><<<gg, blk, 0, stream>>>(AOh, woh, out, SEQ, DM, DM);
}

// Round 5
// 275.978 us; speedup vs baseline: 6.8590x; 1.3992x over previous
//
#include <hip/hip_runtime.h>
#include <math.h>

#define SEQ 4096
#define DM  1024
#define NH  16
#define DH  64

typedef _Float16 h16;
typedef __attribute__((ext_vector_type(4))) _Float16 h16x4;
typedef __attribute__((ext_vector_type(8))) _Float16 h16x8;
typedef __attribute__((ext_vector_type(4))) float f32x4;

// ---------------------------------------------------------------------------
// fp32 -> fp16 conversion, vectorized (n must be multiple of 4)
// ---------------------------------------------------------------------------
__global__ __launch_bounds__(256) void cvt_f32_f16(const float* __restrict__ in,
                                                   h16* __restrict__ out, int n4) {
    const int i = blockIdx.x * 256 + threadIdx.x;
    if (i < n4) {
        const float4 v = ((const float4*)in)[i];
        h16x4 o = { (h16)v.x, (h16)v.y, (h16)v.z, (h16)v.w };
        ((h16x4*)out)[i] = o;
    }
}

// ---------------------------------------------------------------------------
// MFMA GEMM: C[M][N] = A[M][K] @ B[N][K]^T, fp16 in, fp32 accumulate.
// 128x128 tile, BK=32, 256 threads = 4 waves (2x2 of 64x64), reg-prefetch.
// OUT: 0 = h16 row-major [M][N]; 1 = h16 transposed [N][M]; 2 = f32 [M][N].
// ---------------------------------------------------------------------------
#define GST 40

template<int OUT>
__global__ __launch_bounds__(256) void gemm_mfma(const h16* __restrict__ A,
                                                 const h16* __restrict__ B,
                                                 void* __restrict__ Cv,
                                                 int M, int N, int K) {
    __shared__ h16 As[128 * GST];
    __shared__ h16 Bs[128 * GST];

    const int t    = threadIdx.x;
    const int lane = t & 63;
    const int w    = t >> 6;
    const int wm   = (w >> 1) * 64;
    const int wn   = (w & 1) * 64;
    const int l15  = lane & 15;
    const int lq8  = (lane >> 4) * 8;
    const int m0   = blockIdx.y * 128;
    const int n0   = blockIdx.x * 128;

    const int lrow = t >> 2;          // 0..63 (covers rows r and r+64)
    const int lcol = (t & 3) * 8;     // 0,8,16,24 within BK=32

    f32x4 acc[4][4] = {};

    const h16* pA0 = A + (size_t)(m0 + lrow) * K + lcol;
    const h16* pA1 = A + (size_t)(m0 + 64 + lrow) * K + lcol;
    const h16* pB0 = B + (size_t)(n0 + lrow) * K + lcol;
    const h16* pB1 = B + (size_t)(n0 + 64 + lrow) * K + lcol;

    h16x8 ra0 = *(const h16x8*)pA0;
    h16x8 ra1 = *(const h16x8*)pA1;
    h16x8 rb0 = *(const h16x8*)pB0;
    h16x8 rb1 = *(const h16x8*)pB1;

    for (int k0 = 0; k0 < K; k0 += 32) {
        __syncthreads();
        *(h16x8*)&As[lrow * GST + lcol]        = ra0;
        *(h16x8*)&As[(64 + lrow) * GST + lcol] = ra1;
        *(h16x8*)&Bs[lrow * GST + lcol]        = rb0;
        *(h16x8*)&Bs[(64 + lrow) * GST + lcol] = rb1;
        __syncthreads();
        if (k0 + 32 < K) {
            ra0 = *(const h16x8*)(pA0 + k0 + 32);
            ra1 = *(const h16x8*)(pA1 + k0 + 32);
            rb0 = *(const h16x8*)(pB0 + k0 + 32);
            rb1 = *(const h16x8*)(pB1 + k0 + 32);
        }
        h16x8 af[4], bf[4];
        #pragma unroll
        for (int i = 0; i < 4; ++i)
            af[i] = *(const h16x8*)&As[(wm + i * 16 + l15) * GST + lq8];
        #pragma unroll
        for (int j = 0; j < 4; ++j)
            bf[j] = *(const h16x8*)&Bs[(wn + j * 16 + l15) * GST + lq8];
        #pragma unroll
        for (int i = 0; i < 4; ++i)
            #pragma unroll
            for (int j = 0; j < 4; ++j)
                acc[i][j] = __builtin_amdgcn_mfma_f32_16x16x32_f16(af[i], bf[j], acc[i][j], 0, 0, 0);
    }

    const int cr = wm + (lane >> 4) * 4;
    const int cc = wn + l15;
    #pragma unroll
    for (int i = 0; i < 4; ++i)
        #pragma unroll
        for (int j = 0; j < 4; ++j)
            #pragma unroll
            for (int r = 0; r < 4; ++r) {
                const int gm = m0 + cr + i * 16 + r;
                const int gn = n0 + cc + j * 16;
                if (OUT == 2)      ((float*)Cv)[(size_t)gm * N + gn] = acc[i][j][r];
                else if (OUT == 0) ((h16*)Cv)[(size_t)gm * N + gn] = (h16)acc[i][j][r];
                else               ((h16*)Cv)[(size_t)gn * M + gm] = (h16)acc[i][j][r];
            }
}

// ---------------------------------------------------------------------------
// MFMA flash attention (causal), S^T formulation.
// Block = (pair of q-tiles {qA, 63-qA}, head): exactly 65 tile-steps/block.
// S^T = K Q^T: C-layout col = q (one q per lane) -> softmax is in-lane + 2 shfl.
// O^T = V^T P^T: P^T round-trips LDS wave-locally (b64 stores / b128 reads).
// Double-buffered K/V staging: ONE barrier per iteration.
// ---------------------------------------------------------------------------
#define AST 80   // h16/row (160 B): frag reads spread evenly across banks

__device__ __forceinline__ void tile_softmax(const f32x4 s[4], float& m_st, float& l_st,
                                             f32x4 o[4], h16* ps_row, bool diag,
                                             int q_loc, int lq) {
    float sv[4][4];
    float mx = m_st;
    #pragma unroll
    for (int jj = 0; jj < 4; ++jj)
        #pragma unroll
        for (int r = 0; r < 4; ++r) {
            float x = s[jj][r] * 0.125f;   // 1/sqrt(64)
            if (diag && (jj * 16 + lq * 4 + r) > q_loc) x = -1e30f;
            sv[jj][r] = x;
            mx = fmaxf(mx, x);
        }
    mx = fmaxf(mx, __shfl_xor(mx, 16, 64));
    mx = fmaxf(mx, __shfl_xor(mx, 32, 64));
    const float alpha = __expf(m_st - mx);
    m_st = mx;
    float sum = 0.0f;
    #pragma unroll
    for (int jj = 0; jj < 4; ++jj) {
        const float p0 = __expf(sv[jj][0] - mx);
        const float p1 = __expf(sv[jj][1] - mx);
        const float p2 = __expf(sv[jj][2] - mx);
        const float p3 = __expf(sv[jj][3] - mx);
        sum += (p0 + p1) + (p2 + p3);
        h16x4 pk = { (h16)p0, (h16)p1, (h16)p2, (h16)p3 };
        *(h16x4*)(ps_row + jj * 16 + lq * 4) = pk;
    }
    sum += __shfl_xor(sum, 16, 64);
    sum += __shfl_xor(sum, 32, 64);
    l_st = l_st * alpha + sum;
    #pragma unroll
    for (int jj = 0; jj < 4; ++jj)
        #pragma unroll
        for (int r = 0; r < 4; ++r)
            o[jj][r] *= alpha;
}

__global__ __launch_bounds__(256, 2) void flash_attn_mfma(
        const h16* __restrict__ Qg, const h16* __restrict__ Kg,
        const h16* __restrict__ Vt, h16* __restrict__ Og) {
    __shared__ h16 Ks[2][64 * AST];   // [k_local][d]
    __shared__ h16 Vs[2][64 * AST];   // [d][k_local]
    __shared__ h16 Ps[128 * AST];     // [q_band][k]: rows 0-63 tile A, 64-127 tile B

    const int qA   = blockIdx.x;          // 0..31
    const int qB   = 63 - qA;             // 32..63  (work: (qA+1)+(qB+1)=65)
    const int hh   = blockIdx.y;
    const int t    = threadIdx.x;
    const int lane = t & 63;
    const int w    = t >> 6;
    const int l15  = lane & 15;
    const int lq   = lane >> 4;
    const int lq8  = lq * 8;
    const int hc   = hh * DH;
    const int q_loc = w * 16 + l15;       // this lane's q within its tile

    const int r1 = t >> 3;                // 0..31
    const int r2 = r1 + 32;
    const int c1 = (t & 7) * 8;

    // stage Q(A) into Ks[0], Q(B) into Vs[0] (reused before loop overwrites)
    {
        const int qa0 = qA * 64, qb0 = qB * 64;
        *(h16x8*)&Ks[0][r1 * AST + c1] = *(const h16x8*)(Qg + (size_t)(qa0 + r1) * DM + hc + c1);
        *(h16x8*)&Ks[0][r2 * AST + c1] = *(const h16x8*)(Qg + (size_t)(qa0 + r2) * DM + hc + c1);
        *(h16x8*)&Vs[0][r1 * AST + c1] = *(const h16x8*)(Qg + (size_t)(qb0 + r1) * DM + hc + c1);
        *(h16x8*)&Vs[0][r2 * AST + c1] = *(const h16x8*)(Qg + (size_t)(qb0 + r2) * DM + hc + c1);
    }
    // preload kt=0 K/V tile into regs
    h16x8 kv1 = *(const h16x8*)(Kg + (size_t)(r1) * DM + hc + c1);
    h16x8 kv2 = *(const h16x8*)(Kg + (size_t)(r2) * DM + hc + c1);
    h16x8 vv1 = *(const h16x8*)(Vt + (size_t)(hc + r1) * SEQ + c1);
    h16x8 vv2 = *(const h16x8*)(Vt + (size_t)(hc + r2) * SEQ + c1);

    __syncthreads();
    h16x8 qfA[2], qfB[2];
    qfA[0] = *(const h16x8*)&Ks[0][q_loc * AST + lq8];
    qfA[1] = *(const h16x8*)&Ks[0][q_loc * AST + 32 + lq8];
    qfB[0] = *(const h16x8*)&Vs[0][q_loc * AST + lq8];
    qfB[1] = *(const h16x8*)&Vs[0][q_loc * AST + 32 + lq8];
    __syncthreads();   // all Q-frag reads drained (waitcnt before barrier) pre-overwrite

    float mA = -1e30f, lA = 0.0f, mB = -1e30f, lB = 0.0f;
    f32x4 oA[4] = {}, oB[4] = {};
    h16* const psA = &Ps[(size_t)q_loc * AST];
    h16* const psB = &Ps[(size_t)(64 + q_loc) * AST];

    for (int kt = 0; kt <= qB; ++kt) {
        h16* const Ksb = &Ks[kt & 1][0];
        h16* const Vsb = &Vs[kt & 1][0];
        *(h16x8*)&Ksb[r1 * AST + c1] = kv1;
        *(h16x8*)&Ksb[r2 * AST + c1] = kv2;
        *(h16x8*)&Vsb[r1 * AST + c1] = vv1;
        *(h16x8*)&Vsb[r2 * AST + c1] = vv2;
        __syncthreads();
        if (kt < qB) {   // prefetch next K/V tile
            const int k0n = (kt + 1) * 64;
            kv1 = *(const h16x8*)(Kg + (size_t)(k0n + r1) * DM + hc + c1);
            kv2 = *(const h16x8*)(Kg + (size_t)(k0n + r2) * DM + hc + c1);
            vv1 = *(const h16x8*)(Vt + (size_t)(hc + r1) * SEQ + k0n + c1);
            vv2 = *(const h16x8*)(Vt + (size_t)(hc + r2) * SEQ + k0n + c1);
        }
        const bool doA = (kt <= qA);

        // ---- S^T = K Q^T : K-frags read once, shared by both tiles ----
        f32x4 sA[4] = {}, sB[4] = {};
        #pragma unroll
        for (int kc = 0; kc < 2; ++kc)
            #pragma unroll
            for (int jj = 0; jj < 4; ++jj) {
                const h16x8 kf = *(const h16x8*)&Ksb[(jj * 16 + l15) * AST + kc * 32 + lq8];
                if (doA) sA[jj] = __builtin_amdgcn_mfma_f32_16x16x32_f16(kf, qfA[kc], sA[jj], 0, 0, 0);
                sB[jj] = __builtin_amdgcn_mfma_f32_16x16x32_f16(kf, qfB[kc], sB[jj], 0, 0, 0);
            }

        // ---- online softmax (in-lane over 16 k + 2 shfls) + P^T store ----
        if (doA) tile_softmax(sA, mA, lA, oA, psA, kt == qA, q_loc, lq);
        tile_softmax(sB, mB, lB, oB, psB, kt == qB, q_loc, lq);

        // wave-local LDS round-trip: drain this wave's P stores, then read
        asm volatile("s_waitcnt lgkmcnt(0)" ::: "memory");
        h16x8 pfA[2], pfB[2];
        if (doA) {
            pfA[0] = *(const h16x8*)(psA + lq8);        // own row q_loc: wave-local
            pfA[1] = *(const h16x8*)(psA + 32 + lq8);
        }
        pfB[0] = *(const h16x8*)(psB + lq8);
        pfB[1] = *(const h16x8*)(psB + 32 + lq8);

        // ---- O^T += V^T P^T : V-frags read once, shared by both tiles ----
        #pragma unroll
        for (int kc = 0; kc < 2; ++kc)
            #pragma unroll
            for (int jj = 0; jj < 4; ++jj) {
                const h16x8 vf = *(const h16x8*)&Vsb[(jj * 16 + l15) * AST + kc * 32 + lq8];
                if (doA) oA[jj] = __builtin_amdgcn_mfma_f32_16x16x32_f16(vf, pfA[kc], oA[jj], 0, 0, 0);
                oB[jj] = __builtin_amdgcn_mfma_f32_16x16x32_f16(vf, pfB[kc], oB[jj], 0, 0, 0);
            }
    }

    // ---- epilogue: O = O^T / l, write both tiles (h16x4 per d-chunk) ----
    {
        const float il = 1.0f / lA;
        const size_t qg = (size_t)(qA * 64 + q_loc) * DM + hc;
        #pragma unroll
        for (int jj = 0; jj < 4; ++jj) {
            h16x4 ov = { (h16)(oA[jj][0] * il), (h16)(oA[jj][1] * il),
                         (h16)(oA[jj][2] * il), (h16)(oA[jj][3] * il) };
            *(h16x4*)(Og + qg + jj * 16 + lq * 4) = ov;
        }
    }
    {
        const float il = 1.0f / lB;
        const size_t qg = (size_t)(qB * 64 + q_loc) * DM + hc;
        #pragma unroll
        for (int jj = 0; jj < 4; ++jj) {
            h16x4 ov = { (h16)(oB[jj][0] * il), (h16)(oB[jj][1] * il),
                         (h16)(oB[jj][2] * il), (h16)(oB[jj][3] * il) };
            *(h16x4*)(Og + qg + jj * 16 + lq * 4) = ov;
        }
    }
}

// ---------------------------------------------------------------------------
extern "C" void kernel_launch(void* const* d_in, const int* in_sizes, int n_in,
                              void* d_out, int out_size, void* d_ws, size_t ws_size,
                              hipStream_t stream) {
    const float* x  = (const float*)d_in[0];
    const float* Wq = (const float*)d_in[1];
    const float* Wk = (const float*)d_in[2];
    const float* Wv = (const float*)d_in[3];
    const float* Wo = (const float*)d_in[4];
    float* out = (float*)d_out;

    const size_t SD = (size_t)SEQ * DM;   // 4M
    const size_t DD = (size_t)DM * DM;    // 1M

    h16* xh  = (h16*)d_ws;
    h16* wqh = xh + SD;
    h16* wkh = wqh + DD;
    h16* wvh = wkh + DD;
    h16* woh = wvh + DD;
    h16* Qh  = woh + DD;
    h16* Kh  = Qh + SD;
    h16* Vth = Kh + SD;     // transposed: [DM][SEQ]
    h16* AOh = Vth + SD;

    cvt_f32_f16<<<(int)(SD / 4 / 256), 256, 0, stream>>>(x,  xh,  (int)(SD / 4));
    cvt_f32_f16<<<(int)(DD / 4 / 256), 256, 0, stream>>>(Wq, wqh, (int)(DD / 4));
    cvt_f32_f16<<<(int)(DD / 4 / 256), 256, 0, stream>>>(Wk, wkh, (int)(DD / 4));
    cvt_f32_f16<<<(int)(DD / 4 / 256), 256, 0, stream>>>(Wv, wvh, (int)(DD / 4));
    cvt_f32_f16<<<(int)(DD / 4 / 256), 256, 0, stream>>>(Wo, woh, (int)(DD / 4));

    const dim3 blk(256);
    const dim3 gg(DM / 128, SEQ / 128);   // (8, 32)

    gemm_mfma<0><<<gg, blk, 0, stream>>>(xh, wqh, Qh,  SEQ, DM, DM);
    gemm_mfma<0><<<gg, blk, 0, stream>>>(xh, wkh, Kh,  SEQ, DM, DM);
    gemm_mfma<1><<<gg, blk, 0, stream>>>(xh, wvh, Vth, SEQ, DM, DM);   // V^T out

    flash_attn_mfma<<<dim3(32, NH), blk, 0, stream>>>(Qh, Kh, Vth, AOh);

    gemm_mfma<2><<<gg, blk, 0, stream>>>(AOh, woh, out, SEQ, DM, DM);
}